// Round 1
// baseline (198.057 us; speedup 1.0000x reference)
//
#include <hip/hip_runtime.h>
#include <hip/hip_bf16.h>

typedef __bf16 bf16x8_t __attribute__((ext_vector_type(8)));
typedef float f32x4_t __attribute__((ext_vector_type(4)));

#define MFMA_BF16(a, b, c) __builtin_amdgcn_mfma_f32_16x16x32_bf16((a), (b), (c), 0, 0, 0)

static constexpr int T_DIM = 512;
static constexpr int H_DIM = 7168;
static constexpr int F_DIM = 2048;

__device__ __forceinline__ ushort f2bf(float f) {
    return __builtin_bit_cast(ushort, __float2bfloat16(f));
}

// XOR-swizzle for [rows][64-ushort] LDS tiles, 16B-unit granularity.
// c16 in [0,8): 16B-unit column. Returns ushort index.
__device__ __forceinline__ int swzu(int row, int c16) {
    return (row << 6) + (((c16) ^ (row & 7)) << 3);
}
// 8B-granular variant for staging writes (c8 in [0,16))
__device__ __forceinline__ int swz8(int row, int c8) {
    return (row << 6) + ((((c8 >> 1) ^ (row & 7))) << 3) + ((c8 & 1) << 2);
}

__global__ void cvt_x_kernel(const float* __restrict__ in, ushort* __restrict__ outp, int n4) {
    int i = blockIdx.x * 256 + threadIdx.x;
    if (i < n4) {
        float4 v = reinterpret_cast<const float4*>(in)[i];
        ushort4 o;
        o.x = f2bf(v.x); o.y = f2bf(v.y); o.z = f2bf(v.z); o.w = f2bf(v.w);
        reinterpret_cast<ushort4*>(outp)[i] = o;
    }
}

// ---------------- gate+up fused GEMM ----------------
// BM=64, BN=64, BK=64. Grid (F/64=32, T/64=8): x=bn (fast) so same-bn blocks
// land on the same XCD (linear%8 == bn%8) -> weight k-tiles L2-shared across
// the 8 bm-blocks. 4 waves in 2x2, each wave 32x32 out, 2x2 frags per matrix.
__global__ __launch_bounds__(256) void gate_up_kernel(
    const ushort* __restrict__ xb, const float* __restrict__ wg,
    const float* __restrict__ sg, const float* __restrict__ wu,
    const float* __restrict__ su, ushort* __restrict__ hb)
{
    __shared__ ushort As[64 * 64];
    __shared__ ushort Bg[64 * 64];
    __shared__ ushort Bu[64 * 64];

    const int tid = threadIdx.x;
    const int lane = tid & 63;
    const int wid = tid >> 6;
    const int wr = wid >> 1, wc = wid & 1;
    const int bn = blockIdx.x, bm = blockIdx.y;
    const int m0 = bm * 64, n0 = bn * 64;

    const int xr = tid >> 3, xc = tid & 7;      // x staging: rows xr, xr+32
    const int wrow = tid >> 4, wc4 = tid & 15;  // w staging: rows wrow + p*16

    uint4 rx[2];
    float4 rg[4], ru[4];
    const int NT = H_DIM / 64;  // 112

    auto LOAD = [&](int kt) {
        const int k0 = kt * 64;
        #pragma unroll
        for (int p = 0; p < 2; ++p)
            rx[p] = *reinterpret_cast<const uint4*>(
                &xb[(size_t)(m0 + p * 32 + xr) * H_DIM + k0 + xc * 8]);
        #pragma unroll
        for (int p = 0; p < 4; ++p) {
            const size_t off = (size_t)(n0 + p * 16 + wrow) * H_DIM + k0 + wc4 * 4;
            rg[p] = *reinterpret_cast<const float4*>(&wg[off]);
            ru[p] = *reinterpret_cast<const float4*>(&wu[off]);
        }
    };

    f32x4_t accg[2][2] = {};
    f32x4_t accu[2][2] = {};

    LOAD(0);
    for (int kt = 0; kt < NT; ++kt) {
        __syncthreads();
        {   // STORE to LDS (dequant + cvt fused for weights)
            const float s_g = sg[(bn >> 1) * (H_DIM / 128) + (kt >> 1)];
            const float s_u = su[(bn >> 1) * (H_DIM / 128) + (kt >> 1)];
            #pragma unroll
            for (int p = 0; p < 2; ++p)
                *reinterpret_cast<uint4*>(&As[swzu(p * 32 + xr, xc)]) = rx[p];
            #pragma unroll
            for (int p = 0; p < 4; ++p) {
                const int row = p * 16 + wrow;
                ushort4 g4, u4;
                g4.x = f2bf(rg[p].x * s_g); g4.y = f2bf(rg[p].y * s_g);
                g4.z = f2bf(rg[p].z * s_g); g4.w = f2bf(rg[p].w * s_g);
                u4.x = f2bf(ru[p].x * s_u); u4.y = f2bf(ru[p].y * s_u);
                u4.z = f2bf(ru[p].z * s_u); u4.w = f2bf(ru[p].w * s_u);
                *reinterpret_cast<ushort4*>(&Bg[swz8(row, wc4)]) = g4;
                *reinterpret_cast<ushort4*>(&Bu[swz8(row, wc4)]) = u4;
            }
        }
        __syncthreads();
        if (kt + 1 < NT) LOAD(kt + 1);  // prefetch overlaps MFMA below
        #pragma unroll
        for (int ks = 0; ks < 2; ++ks) {
            const int ku = ks * 4 + (lane >> 4);
            bf16x8_t af[2], gf[2], uf[2];
            #pragma unroll
            for (int i = 0; i < 2; ++i)
                af[i] = *reinterpret_cast<const bf16x8_t*>(
                    &As[swzu(wr * 32 + i * 16 + (lane & 15), ku)]);
            #pragma unroll
            for (int j = 0; j < 2; ++j) {
                gf[j] = *reinterpret_cast<const bf16x8_t*>(
                    &Bg[swzu(wc * 32 + j * 16 + (lane & 15), ku)]);
                uf[j] = *reinterpret_cast<const bf16x8_t*>(
                    &Bu[swzu(wc * 32 + j * 16 + (lane & 15), ku)]);
            }
            #pragma unroll
            for (int i = 0; i < 2; ++i)
                #pragma unroll
                for (int j = 0; j < 2; ++j) {
                    accg[i][j] = MFMA_BF16(af[i], gf[j], accg[i][j]);
                    accu[i][j] = MFMA_BF16(af[i], uf[j], accu[i][j]);
                }
        }
    }

    // epilogue: h = silu(g) * u, bf16
    #pragma unroll
    for (int i = 0; i < 2; ++i)
        #pragma unroll
        for (int j = 0; j < 2; ++j)
            #pragma unroll
            for (int r = 0; r < 4; ++r) {
                const int m = m0 + wr * 32 + i * 16 + (lane >> 4) * 4 + r;
                const int n = n0 + wc * 32 + j * 16 + (lane & 15);
                const float g = accg[i][j][r];
                const float u = accu[i][j][r];
                const float sil = g / (1.0f + __expf(-g));
                hb[(size_t)m * F_DIM + n] = f2bf(sil * u);
            }
}

// ---------------- down GEMM ----------------
// BM=64, BN=128, BK=64. Grid (H/128=56, T/64=8). 4 waves 2x2, each 32x64.
__global__ __launch_bounds__(256) void down_kernel(
    const ushort* __restrict__ hb, const float* __restrict__ wd,
    const float* __restrict__ sd, float* __restrict__ out)
{
    __shared__ ushort As[64 * 64];
    __shared__ ushort Bs[128 * 64];

    const int tid = threadIdx.x;
    const int lane = tid & 63;
    const int wid = tid >> 6;
    const int wr = wid >> 1, wc = wid & 1;
    const int bn = blockIdx.x, bm = blockIdx.y;
    const int m0 = bm * 64, n0 = bn * 128;

    const int xr = tid >> 3, xc = tid & 7;
    const int wrow = tid >> 4, wc4 = tid & 15;

    uint4 rx[2];
    float4 rw[8];
    const int NT = F_DIM / 64;  // 32

    auto LOAD = [&](int kt) {
        const int k0 = kt * 64;
        #pragma unroll
        for (int p = 0; p < 2; ++p)
            rx[p] = *reinterpret_cast<const uint4*>(
                &hb[(size_t)(m0 + p * 32 + xr) * F_DIM + k0 + xc * 8]);
        #pragma unroll
        for (int p = 0; p < 8; ++p)
            rw[p] = *reinterpret_cast<const float4*>(
                &wd[(size_t)(n0 + p * 16 + wrow) * F_DIM + k0 + wc4 * 4]);
    };

    f32x4_t acc[2][4] = {};

    LOAD(0);
    for (int kt = 0; kt < NT; ++kt) {
        __syncthreads();
        {
            const float s_d = sd[bn * (F_DIM / 128) + (kt >> 1)];
            #pragma unroll
            for (int p = 0; p < 2; ++p)
                *reinterpret_cast<uint4*>(&As[swzu(p * 32 + xr, xc)]) = rx[p];
            #pragma unroll
            for (int p = 0; p < 8; ++p) {
                const int row = p * 16 + wrow;
                ushort4 w4;
                w4.x = f2bf(rw[p].x * s_d); w4.y = f2bf(rw[p].y * s_d);
                w4.z = f2bf(rw[p].z * s_d); w4.w = f2bf(rw[p].w * s_d);
                *reinterpret_cast<ushort4*>(&Bs[swz8(row, wc4)]) = w4;
            }
        }
        __syncthreads();
        if (kt + 1 < NT) LOAD(kt + 1);
        #pragma unroll
        for (int ks = 0; ks < 2; ++ks) {
            const int ku = ks * 4 + (lane >> 4);
            bf16x8_t af[2], bfr[4];
            #pragma unroll
            for (int i = 0; i < 2; ++i)
                af[i] = *reinterpret_cast<const bf16x8_t*>(
                    &As[swzu(wr * 32 + i * 16 + (lane & 15), ku)]);
            #pragma unroll
            for (int j = 0; j < 4; ++j)
                bfr[j] = *reinterpret_cast<const bf16x8_t*>(
                    &Bs[swzu(wc * 64 + j * 16 + (lane & 15), ku)]);
            #pragma unroll
            for (int i = 0; i < 2; ++i)
                #pragma unroll
                for (int j = 0; j < 4; ++j)
                    acc[i][j] = MFMA_BF16(af[i], bfr[j], acc[i][j]);
        }
    }

    #pragma unroll
    for (int i = 0; i < 2; ++i)
        #pragma unroll
        for (int j = 0; j < 4; ++j)
            #pragma unroll
            for (int r = 0; r < 4; ++r) {
                const int m = m0 + wr * 32 + i * 16 + (lane >> 4) * 4 + r;
                const int n = n0 + wc * 64 + j * 16 + (lane & 15);
                out[(size_t)m * H_DIM + n] = acc[i][j][r];
            }
}

extern "C" void kernel_launch(void* const* d_in, const int* in_sizes, int n_in,
                              void* d_out, int out_size, void* d_ws, size_t ws_size,
                              hipStream_t stream) {
    const float* x  = (const float*)d_in[0];
    const float* wg = (const float*)d_in[1];
    const float* sg = (const float*)d_in[2];
    const float* wu = (const float*)d_in[3];
    const float* su = (const float*)d_in[4];
    const float* wd = (const float*)d_in[5];
    const float* sd = (const float*)d_in[6];
    float* out = (float*)d_out;

    ushort* xb = (ushort*)d_ws;                      // 512*7168 bf16 = 7.0 MiB
    ushort* hb = xb + (size_t)T_DIM * H_DIM;         // 512*2048 bf16 = 2.0 MiB

    const int n4 = T_DIM * H_DIM / 4;
    cvt_x_kernel<<<n4 / 256, 256, 0, stream>>>(x, xb, n4);
    gate_up_kernel<<<dim3(F_DIM / 64, T_DIM / 64), 256, 0, stream>>>(xb, wg, sg, wu, su, hb);
    down_kernel<<<dim3(H_DIM / 128, T_DIM / 64), 256, 0, stream>>>(hb, wd, sd, out);
}